// Round 5
// baseline (119.694 us; speedup 1.0000x reference)
//
#include <hip/hip_runtime.h>
#include <math.h>

#define NN    8192
#define KF    512
#define DF    64
#define NCH   32
#define EC    136   // E row stride: [pos h1 0..63][neg h1 64..127][onesP 128][onesN 129][pad]

// ============ K1: blocks 0..255:  h1 = x@W^T   (64 rows x 32 cols per block)
// ============     blocks 256..511: s2 = n@(W^T w2), 32 rows each
__global__ __launch_bounds__(256) void k_main(const float* __restrict__ x,
        const float* __restrict__ nmat, const float* __restrict__ W,
        const float* __restrict__ w2,
        float* __restrict__ h1, float* __restrict__ s2) {
    __shared__ float xs[64 * 128];   // 32 KB (GEMM) / aliased as v2s (s2 path)
    const int tid = threadIdx.x;
    if (blockIdx.x < 256) {
        const int row0 = (blockIdx.x >> 1) * 64;
        const int c0   = (blockIdx.x & 1) * 32;
        const int l = tid & 63;
        const int w = __builtin_amdgcn_readfirstlane(tid >> 6);
        const int d0 = c0 + w * 8;            // wave-uniform col base
        float acc[8] = {};
        float4 pf[8];
        #pragma unroll
        for (int q = 0; q < 8; ++q) {
            const int idx = q * 256 + tid, r = idx >> 5, c4 = (idx & 31) * 4;
            pf[q] = *reinterpret_cast<const float4*>(x + (size_t)(row0 + r) * KF + c4);
        }
        for (int kc = 0; kc < 4; ++kc) {
            __syncthreads();
            #pragma unroll
            for (int q = 0; q < 8; ++q) {
                const int idx = q * 256 + tid, r = idx >> 5, c4 = (idx & 31) * 4;
                *reinterpret_cast<float4*>(&xs[r * 128 + (c4 ^ ((r & 7) << 2))]) = pf[q];
            }
            __syncthreads();
            if (kc < 3) {
                #pragma unroll
                for (int q = 0; q < 8; ++q) {
                    const int idx = q * 256 + tid, r = idx >> 5, c4 = (idx & 31) * 4;
                    pf[q] = *reinterpret_cast<const float4*>(
                        x + (size_t)(row0 + r) * KF + (kc + 1) * 128 + c4);
                }
            }
            const float* Wb = W + (size_t)d0 * KF + kc * 128;   // uniform
            #pragma unroll 4
            for (int q = 0; q < 32; ++q) {
                const float4 a = *reinterpret_cast<const float4*>(
                    &xs[l * 128 + ((q * 4) ^ ((l & 7) << 2))]);
                #pragma unroll
                for (int j = 0; j < 8; ++j) {
                    const float4 b = *reinterpret_cast<const float4*>(Wb + (size_t)j * KF + q * 4);
                    acc[j] = fmaf(a.x, b.x, fmaf(a.y, b.y, fmaf(a.z, b.z, fmaf(a.w, b.w, acc[j]))));
                }
            }
        }
        *reinterpret_cast<float4*>(h1 + (size_t)(row0 + l) * DF + d0) =
            make_float4(acc[0], acc[1], acc[2], acc[3]);
        *reinterpret_cast<float4*>(h1 + (size_t)(row0 + l) * DF + d0 + 4) =
            make_float4(acc[4], acc[5], acc[6], acc[7]);
    } else {
        float* v2s = xs;
        const int row0 = (int)(blockIdx.x - 256) * 32;
        float a0 = 0.f, a1 = 0.f;
        for (int d = 0; d < DF; ++d) {
            const float wd2 = w2[d];
            a0 = fmaf(W[(size_t)d * KF + tid],       wd2, a0);
            a1 = fmaf(W[(size_t)d * KF + 256 + tid], wd2, a1);
        }
        v2s[tid] = a0; v2s[tid + 256] = a1;
        __syncthreads();
        const int lane = tid & 63, w = tid >> 6;
        const float4 b0 = *reinterpret_cast<const float4*>(&v2s[lane * 4]);
        const float4 b1 = *reinterpret_cast<const float4*>(&v2s[256 + lane * 4]);
        for (int rr = 0; rr < 8; ++rr) {
            const int row = row0 + w * 8 + rr;
            const float4 n0 = *reinterpret_cast<const float4*>(nmat + (size_t)row * KF + lane * 4);
            const float4 n1 = *reinterpret_cast<const float4*>(nmat + (size_t)row * KF + 256 + lane * 4);
            float acc = n0.x * b0.x;
            acc = fmaf(n0.y, b0.y, acc); acc = fmaf(n0.z, b0.z, acc); acc = fmaf(n0.w, b0.w, acc);
            acc = fmaf(n1.x, b1.x, acc); acc = fmaf(n1.y, b1.y, acc);
            acc = fmaf(n1.z, b1.z, acc); acc = fmaf(n1.w, b1.w, acc);
            #pragma unroll
            for (int off = 32; off; off >>= 1) acc += __shfl_xor(acc, off);
            if (lane == 0) s2[row] = acc;
        }
    }
}

__device__ __forceinline__ unsigned int f2key(float f) {
    unsigned int u = __float_as_uint(f);
    return u ^ ((u >> 31) ? 0xFFFFFFFFu : 0x80000000u);
}

// ============ K2: rank by (s2, idx); 2 j's per thread share each staged key read
__global__ __launch_bounds__(256) void k_rank(const float* __restrict__ s2,
        int* __restrict__ order, float* __restrict__ s2s,
        double* __restrict__ wpos, double* __restrict__ wneg) {
    __shared__ unsigned int sk[NN];   // 32 KB
    __shared__ int2 part[8][32];
    const int tid = threadIdx.x;
    {
        const float4* src = reinterpret_cast<const float4*>(s2);
        #pragma unroll
        for (int t = 0; t < 8; ++t) {
            const float4 v = src[tid + t * 256];
            const int b = (tid + t * 256) * 4;
            sk[b] = f2key(v.x); sk[b+1] = f2key(v.y); sk[b+2] = f2key(v.z); sk[b+3] = f2key(v.w);
        }
    }
    __syncthreads();
    const int jl = tid & 7, seg = tid >> 3;
    const int j0 = blockIdx.x * 16 + jl, j1 = j0 + 8;
    const unsigned int k0 = sk[j0], k1 = sk[j1];
    const int base = seg * 256;
    int c0 = 0, c1 = 0;
    for (int q = 0; q < 64; ++q) {
        const int qq = (q + seg) & 63;       // stagger: 8 distinct bank-groups per wave
        const int idx = base + qq * 4;
        const uint4 v = *reinterpret_cast<const uint4*>(&sk[idx]);
        c0 += (v.x < k0) | ((v.x == k0) & (idx     < j0));
        c0 += (v.y < k0) | ((v.y == k0) & (idx + 1 < j0));
        c0 += (v.z < k0) | ((v.z == k0) & (idx + 2 < j0));
        c0 += (v.w < k0) | ((v.w == k0) & (idx + 3 < j0));
        c1 += (v.x < k1) | ((v.x == k1) & (idx     < j1));
        c1 += (v.y < k1) | ((v.y == k1) & (idx + 1 < j1));
        c1 += (v.z < k1) | ((v.z == k1) & (idx + 2 < j1));
        c1 += (v.w < k1) | ((v.w == k1) & (idx + 3 < j1));
    }
    part[jl][seg] = make_int2(c0, c1);
    __syncthreads();
    if (tid < 16) {
        const int jloc = tid & 7, hi = tid >> 3;
        int r = 0;
        #pragma unroll
        for (int s = 0; s < 32; ++s) r += hi ? part[jloc][s].y : part[jloc][s].x;
        const int jj = blockIdx.x * 16 + jloc + 8 * hi;
        const float v = s2[jj];
        order[r] = jj;
        s2s[r] = v;
        wpos[r] = exp((double)v);
        wneg[r] = exp(0.2 * (double)v);
    }
}

// col-group helpers: g<8 -> pos h1 cols 8g..; g<16 -> neg h1; g==16 -> ones {128,129}
__device__ __forceinline__ void load_vals(int g, int p, const float* __restrict__ h1,
        const int* __restrict__ order, const double* __restrict__ wpos,
        const double* __restrict__ wneg, double* vals, int& ncols, int& colbase) {
    if (g < 16) {
        ncols = 8;
        const int d0 = (g < 8) ? 8 * g : 8 * (g - 8);
        colbase = (g < 8) ? d0 : 64 + d0;
        const double wgt = (g < 8) ? wpos[p] : wneg[p];
        const float* hp = h1 + (size_t)order[p] * DF + d0;
        const float4 h0 = *reinterpret_cast<const float4*>(hp);
        const float4 h4 = *reinterpret_cast<const float4*>(hp + 4);
        vals[0]=wgt*h0.x; vals[1]=wgt*h0.y; vals[2]=wgt*h0.z; vals[3]=wgt*h0.w;
        vals[4]=wgt*h4.x; vals[5]=wgt*h4.y; vals[6]=wgt*h4.z; vals[7]=wgt*h4.w;
    } else {
        ncols = 2; colbase = 128;
        vals[0] = wpos[p]; vals[1] = wneg[p];
    }
}

// ============ K3: per-(col,chunk) totals
__global__ __launch_bounds__(256) void k_csum(const float* __restrict__ h1,
        const int* __restrict__ order, const double* __restrict__ wpos,
        const double* __restrict__ wneg, double* __restrict__ cT) {
    const int g = blockIdx.x, c = blockIdx.y;
    const int tid = threadIdx.x, lane = tid & 63, w = tid >> 6;
    const int p = c * 256 + tid;
    double vals[8]; int ncols, colbase;
    load_vals(g, p, h1, order, wpos, wneg, vals, ncols, colbase);
    __shared__ double red[4][8];
    for (int jj = 0; jj < ncols; ++jj) {
        double r = vals[jj];
        #pragma unroll
        for (int off = 32; off; off >>= 1) r += __shfl_xor(r, off);
        if (lane == 0) red[w][jj] = r;
    }
    __syncthreads();
    if (tid < ncols)
        cT[(size_t)(colbase + tid) * NCH + c] = red[0][tid] + red[1][tid] + red[2][tid] + red[3][tid];
}

// ============ K4: exclusive scan -> E (8-col contiguous 64B line stores)
__global__ __launch_bounds__(256) void k_scan(const float* __restrict__ h1,
        const int* __restrict__ order, const double* __restrict__ wpos,
        const double* __restrict__ wneg, const double* __restrict__ cT,
        double* __restrict__ E) {
    const int g = blockIdx.x, c = blockIdx.y;
    const int tid = threadIdx.x, lane = tid & 63, w = tid >> 6;
    const int p = c * 256 + tid;
    double vals[8], inc8[8]; int ncols, colbase;
    load_vals(g, p, h1, order, wpos, wneg, vals, ncols, colbase);
    __shared__ double cOs[8];
    __shared__ double wtot[4][8];
    if (tid < ncols) {
        double s = 0.0;
        const double* ct = cT + (size_t)(colbase + tid) * NCH;
        for (int cc = 0; cc < c; ++cc) s += ct[cc];
        cOs[tid] = s;
    }
    for (int jj = 0; jj < ncols; ++jj) {
        double incl = vals[jj];
        #pragma unroll
        for (int off = 1; off < 64; off <<= 1) {
            double t = __shfl_up(incl, off);
            if (lane >= off) incl += t;
        }
        inc8[jj] = incl;
        if (lane == 63) wtot[w][jj] = incl;
    }
    __syncthreads();
    double* Ep = E + (size_t)p * EC + colbase;
    for (int jj = 0; jj < ncols; ++jj) {
        double woff = cOs[jj];
        for (int ww = 0; ww < w; ++ww) woff += wtot[ww][jj];
        Ep[jj] = woff + inc8[jj] - vals[jj];
    }
    if (c == NCH - 1 && tid < ncols)
        E[(size_t)NN * EC + colbase + tid] =
            cOs[tid] + wtot[0][tid] + wtot[1][tid] + wtot[2][tid] + wtot[3][tid];
}

// ============ K5: s1 inline + LDS-staged binary search + combine (16 rows/block)
__global__ __launch_bounds__(256) void k_out(const float* __restrict__ h1,
        const float* __restrict__ w1, const float* __restrict__ s2s,
        const double* __restrict__ E, float* __restrict__ out) {
    __shared__ float ss[NN];   // 32 KB sorted keys
    const int tid = threadIdx.x;
    {
        const float4* src = reinterpret_cast<const float4*>(s2s);
        float4* dst = reinterpret_cast<float4*>(ss);
        #pragma unroll
        for (int t = 0; t < 8; ++t) dst[tid + t * 256] = src[tid + t * 256];
    }
    __syncthreads();
    const int lane = tid & 63, w = tid >> 6;
    const int i0 = blockIdx.x * 16 + w * 4;
    const float wl = w1[lane];
    float s1v[4];
    #pragma unroll
    for (int r = 0; r < 4; ++r) {
        float p = h1[(size_t)(i0 + r) * DF + lane] * wl;
        #pragma unroll
        for (int off = 32; off; off >>= 1) p += __shfl_xor(p, off);
        s1v[r] = p;
    }
    int lo[4] = {0, 0, 0, 0}, hi[4] = {NN, NN, NN, NN};
    for (int step = 0; step < 13; ++step) {
        #pragma unroll
        for (int r = 0; r < 4; ++r) {
            const int mid = (lo[r] + hi[r]) >> 1;
            if (ss[mid] < -s1v[r]) lo[r] = mid + 1; else hi[r] = mid;
        }
    }
    const double* Et = E + (size_t)NN * EC;
    #pragma unroll
    for (int r = 0; r < 4; ++r) {
        const double* Ek = E + (size_t)lo[r] * EC;
        const double e1 = exp((double)s1v[r]);
        const double e2 = exp(0.2 * (double)s1v[r]);
        const double num = e1 * (Et[lane] - Ek[lane]) + e2 * Ek[64 + lane];
        const double den = e1 * (Et[128] - Ek[128]) + e2 * Ek[129];
        out[(size_t)(i0 + r) * DF + lane] = (float)(num / den);
    }
}

extern "C" void kernel_launch(void* const* d_in, const int* in_sizes, int n_in,
                              void* d_out, int out_size, void* d_ws, size_t ws_size,
                              hipStream_t stream) {
    const float* x    = (const float*)d_in[0];
    const float* nmat = (const float*)d_in[1];
    const float* W    = (const float*)d_in[2];
    const float* w1   = (const float*)d_in[3];
    const float* w2   = (const float*)d_in[4];
    float* out = (float*)d_out;

    char* ws = (char*)d_ws;
    size_t off = 0;
    auto alloc = [&](size_t bytes) -> void* {
        void* p = ws + off;
        off += (bytes + 255) & ~(size_t)255;
        return p;
    };
    float*  h1    = (float*)alloc((size_t)NN * DF * 4);        // 2 MB
    float*  s2    = (float*)alloc((size_t)NN * 4);
    int*    order = (int*)alloc((size_t)NN * 4);
    float*  s2s   = (float*)alloc((size_t)NN * 4);
    double* wpos  = (double*)alloc((size_t)NN * 8);
    double* wneg  = (double*)alloc((size_t)NN * 8);
    double* cT    = (double*)alloc((size_t)130 * NCH * 8);
    double* E     = (double*)alloc((size_t)(NN + 1) * EC * 8); // 8.9 MB

    k_main<<<512, 256, 0, stream>>>(x, nmat, W, w2, h1, s2);
    k_rank<<<512, 256, 0, stream>>>(s2, order, s2s, wpos, wneg);
    k_csum<<<dim3(17, NCH), 256, 0, stream>>>(h1, order, wpos, wneg, cT);
    k_scan<<<dim3(17, NCH), 256, 0, stream>>>(h1, order, wpos, wneg, cT, E);
    k_out<<<NN / 16, 256, 0, stream>>>(h1, w1, s2s, E, out);
}